// Round 9
// baseline (271.031 us; speedup 1.0000x reference)
//
#include <hip/hip_runtime.h>
#include <math.h>

// Problem constants
#define B_   8
#define T_   2048
#define V_   1024
#define C_   128
#define NB2  64     // 2*NB
#define L_   32     // chunk length for the linearized recurrence
#define NC_  64     // T_/L_

typedef _Float16 f16_t;
typedef f16_t f16x8 __attribute__((ext_vector_type(8)));
typedef float f32x4 __attribute__((ext_vector_type(4)));

__device__ __forceinline__ float sigmoidf_(float x){ return 1.0f/(1.0f+expf(-x)); }

// direct global->LDS DMA, 16 B per lane (dest must be linear: base + lane*16)
__device__ __forceinline__ void gload_lds16(const void* g, void* l){
  __builtin_amdgcn_global_load_lds(
      (const __attribute__((address_space(1))) uint32_t*)g,
      (__attribute__((address_space(3))) uint32_t*)l, 16, 0, 0);
}

// ---------------------------------------------------------------------------
// K0: weights. proj 0..2: softmax(basis@coeffs^T, axis=V) -> fp16,
//     TRANSPOSED (Wt[c][v]) for MFMA B-fragment reads.
//     proj 3: Wo (V,C) row-major fp16 (rows are B-fragments for out GEMM).
// ---------------------------------------------------------------------------
__global__ __launch_bounds__(256) void weights_kernel(
    const float* __restrict__ basis,
    const float* __restrict__ qc, const float* __restrict__ kc,
    const float* __restrict__ vc, const float* __restrict__ oc,
    f16_t* __restrict__ Wo, f16_t* __restrict__ Wt)
{
  int blk  = blockIdx.x;
  int proj = blk >> 7;
  int c    = blk & 127;
  const float* coeffs = (proj==0)?qc : (proj==1)?kc : (proj==2)?vc : oc;

  __shared__ float coef[NB2];
  __shared__ float red[256];
  int tid = threadIdx.x;
  if (tid < NB2) coef[tid] = coeffs[c*NB2 + tid];
  __syncthreads();

  float l[4];
  for (int i=0;i<4;i++){
    int v = tid + i*256;
    const float4* bp = (const float4*)(basis + (size_t)v*NB2);
    float s = 0.f;
    #pragma unroll
    for (int f=0; f<NB2/4; f++){
      float4 b4 = bp[f];
      s += b4.x*coef[f*4+0] + b4.y*coef[f*4+1] + b4.z*coef[f*4+2] + b4.w*coef[f*4+3];
    }
    l[i] = s;
  }
  if (proj == 3){
    for (int i=0;i<4;i++){ int v = tid+i*256; Wo[(size_t)v*C_ + c] = (f16_t)l[i]; }
    return;
  }
  float mx = fmaxf(fmaxf(l[0],l[1]), fmaxf(l[2],l[3]));
  red[tid] = mx; __syncthreads();
  for (int s=128; s>0; s>>=1){ if (tid<s) red[tid] = fmaxf(red[tid], red[tid+s]); __syncthreads(); }
  mx = red[0]; __syncthreads();
  float sum = 0.f;
  for (int i=0;i<4;i++) sum += expf(l[i]-mx);
  red[tid] = sum; __syncthreads();
  for (int s=128; s>0; s>>=1){ if (tid<s) red[tid] += red[tid+s]; __syncthreads(); }
  float inv = 1.0f/red[0];
  f16_t* tp = Wt + ((size_t)proj*C_ + c)*V_;
  for (int i=0;i<4;i++){
    int v = tid+i*256;
    tp[v] = (f16_t)(expf(l[i]-mx)*inv);
  }
}

// ---------------------------------------------------------------------------
// K1 v3 (FUSED, BM 64->32): q,k,v = x @ [Wq|Wk|Wv] in ONE pass over x.
// Round-8 ran grid 256 = exactly 1 block/CU: every barrier-drain exposed.
// BM=32 -> grid 512 = 2 blocks/CU; one block's DMA drain overlaps the
// other's MFMA phase. LDS 52.6 KB (As 4.6 + Bsh 48) -> 2 blocks fit.
// 512 thr = 8 waves (2x4), wave tile 16x96, BK=64, 16 K-iters.
// B staged via global_load_lds (linear LDS, XOR-swizzled source + same XOR
// on ds_read).
// ---------------------------------------------------------------------------
#define BM 64     // out_mfma M-tile
#define BMP 32    // proj M-tile
#define BN 128
#define BK 64
#define PADK 72   // LDS row stride in f16 for A (144 B, breaks pow2 banks)
#define NF_  384  // 3*C
#define NT_PROJ (V_/BK)   // 16

__global__ __launch_bounds__(512, 1) void proj_fused_kernel(
    const float* __restrict__ x,
    const f16_t* __restrict__ Wt,   // [384][1024] f16 (= [3][C][V])
    float* __restrict__ out)        // [3][M][C]
{
  const int M = B_*T_;
  int m0 = blockIdx.x * BMP;

  __shared__ __align__(16) f16_t As[BMP][PADK];  // 4.6 KB
  __shared__ __align__(16) f16_t Bsh[NF_*BK];    // 48 KB, swizzled chunks

  int tid  = threadIdx.x;          // 0..511
  int lane = tid & 63;
  int w    = tid >> 6;             // 0..7
  int wm   = (w >> 2) * 16;        // 0,16
  int wn   = (w & 3) * 96;         // 0,96,192,288
  int lr   = lane & 15;
  int lg   = lane >> 4;

  const float* xbase = x + (size_t)m0*V_;

  f32x4 acc[6] = {};

  for (int kt = 0; kt < NT_PROJ; kt++){
    // B: 384x64 f16 = 3072 16B chunks, 6/thread, DMA to LDS (linear dest,
    // source XOR-swizzled; same XOR on the read below).
    #pragma unroll
    for (int i=0;i<6;i++){
      int ci = i*512 + tid;
      int r  = ci >> 3, ch = ci & 7;
      const f16_t* src = Wt + (size_t)r*V_ + kt*BK + ((ch ^ (r&7))<<3);
      gload_lds16(src, &Bsh[ci*8]);
    }
    // A: 32x64 fp32 -> f16 = 512 float4 chunks, 1/thread
    {
      int row = tid >> 4, qq = tid & 15;
      float4 xv = *(const float4*)(xbase + (size_t)row*V_ + kt*BK + qq*4);
      union { f16_t h[4]; ushort4 u; } hh;
      hh.h[0]=(f16_t)xv.x; hh.h[1]=(f16_t)xv.y; hh.h[2]=(f16_t)xv.z; hh.h[3]=(f16_t)xv.w;
      *(ushort4*)&As[row][qq*4] = hh.u;
    }
    __syncthreads();

    #pragma unroll
    for (int kh=0; kh<2; kh++){
      f16x8 a = *(f16x8*)&As[wm + lr][kh*32 + lg*8];
      #pragma unroll
      for (int nt=0; nt<6; nt++){
        int n  = wn + nt*16 + lr;
        int c0 = kh*4 + lg;
        f16x8 b = *(f16x8*)&Bsh[n*BK + ((c0 ^ (n&7))<<3)];
        acc[nt] = __builtin_amdgcn_mfma_f32_16x16x32_f16(a, b, acc[nt], 0,0,0);
      }
    }
    __syncthreads();
  }

  // epilogue: C/D layout col=lane&15, row=(lane>>4)*4+reg; proj = n>>7
  #pragma unroll
  for (int nt=0; nt<6; nt++){
    int n   = wn + nt*16 + lr;
    int p   = n >> 7;
    int col = n & 127;
    float* op = out + (size_t)p*M*C_;
    #pragma unroll
    for (int r=0; r<4; r++){
      int row = m0 + wm + lg*4 + r;
      op[(size_t)row*C_ + col] = acc[nt][r];
    }
  }
}

// ---------------------------------------------------------------------------
// K2: per-chunk KV summary: kv[b][ci][c][dd] = sum_j d^{L-1-j} k_j[c] v_j[dd]
// ---------------------------------------------------------------------------
__global__ __launch_bounds__(256) void kvsum_kernel(
    const float* __restrict__ k, const float* __restrict__ v,
    const float* __restrict__ dptr, float* __restrict__ kv)
{
  int ci = blockIdx.x, b = blockIdx.y;
  float d = sigmoidf_(dptr[0]);
  __shared__ float ks[L_][132];
  __shared__ float vs[L_][132];
  int tid = threadIdx.x;
  const float* kp = k + ((size_t)b*T_ + ci*L_)*C_;
  const float* vp = v + ((size_t)b*T_ + ci*L_)*C_;
  #pragma unroll
  for (int i=0;i<4;i++){
    int idx = tid + i*256;
    int j = idx >> 5, c4 = idx & 31;
    float w = powf(d, (float)(L_-1-j));
    float4 k4 = *(const float4*)(kp + (size_t)j*C_ + c4*4);
    k4.x*=w; k4.y*=w; k4.z*=w; k4.w*=w;
    *(float4*)&ks[j][c4*4] = k4;
    *(float4*)&vs[j][c4*4] = *(const float4*)(vp + (size_t)j*C_ + c4*4);
  }
  __syncthreads();
  int tc = tid >> 4, td = tid & 15;
  float acc[8][8] = {};
  for (int j=0;j<L_;j++){
    float kr[8], vr[8];
    *(float4*)&kr[0] = *(float4*)&ks[j][tc*8];
    *(float4*)&kr[4] = *(float4*)&ks[j][tc*8+4];
    *(float4*)&vr[0] = *(float4*)&vs[j][td*8];
    *(float4*)&vr[4] = *(float4*)&vs[j][td*8+4];
    #pragma unroll
    for (int a=0;a<8;a++)
      #pragma unroll
      for (int bb=0;bb<8;bb++) acc[a][bb] += kr[a]*vr[bb];
  }
  float* op = kv + ((size_t)b*NC_ + ci)*C_*C_;
  for (int a=0;a<8;a++)
    for (int b4=0;b4<2;b4++)
      *(float4*)(op + (size_t)(tc*8+a)*C_ + td*8 + b4*4) =
        make_float4(acc[a][b4*4],acc[a][b4*4+1],acc[a][b4*4+2],acc[a][b4*4+3]);
}

// ---------------------------------------------------------------------------
// K3 v2: in-place exclusive scan over chunks, UNROLL-4 load prefetch.
// Old: 64 dependent load->store iters = per-wave latency chain (~18us).
// New: groups of 4 -- issue 4 independent loads, then 4 store+fma steps.
// Element-wise op sequence identical (reads precede the group's writes;
// addresses disjoint), so bit-exact.
// ---------------------------------------------------------------------------
__global__ __launch_bounds__(256) void scan_kernel(
    float* __restrict__ kv, const float* __restrict__ dptr)
{
  int idx = blockIdx.x*256 + threadIdx.x;
  int b = idx >> 14, e = idx & 16383;
  float d  = sigmoidf_(dptr[0]);
  float dL = powf(d, (float)L_);
  float* p = kv + (size_t)b*NC_*C_*C_ + e;
  const size_t S = (size_t)C_*C_;   // 16384
  float m = 0.f;
  #pragma unroll 4
  for (int g=0; g<NC_/4; g++){
    float s0 = p[(size_t)(4*g+0)*S];
    float s1 = p[(size_t)(4*g+1)*S];
    float s2 = p[(size_t)(4*g+2)*S];
    float s3 = p[(size_t)(4*g+3)*S];
    p[(size_t)(4*g+0)*S] = m;  m = dL*m + s0;
    p[(size_t)(4*g+1)*S] = m;  m = dL*m + s1;
    p[(size_t)(4*g+2)*S] = m;  m = dL*m + s2;
    p[(size_t)(4*g+3)*S] = m;  m = dL*m + s3;
  }
}

// ---------------------------------------------------------------------------
// K4 v5 (kept): WHOLE-M intra. 64KB M staged in one global_load_lds burst,
// 3 barriers, q@M as a single unbroken 128-iter LDS loop. 43.7us measured.
// ---------------------------------------------------------------------------
__global__ __launch_bounds__(256) void intra_kernel(
    const float* __restrict__ q, const float* __restrict__ k,
    const float* __restrict__ v, const float* __restrict__ Minit,
    const float* __restrict__ dptr,
    f16_t* __restrict__ ret)
{
  int ci = blockIdx.x, b = blockIdx.y;
  int tid = threadIdx.x;
  float d = sigmoidf_(dptr[0]);
  __shared__ float qs[L_][132];
  __shared__ float kvs[L_][132];               // k for scores, then v
  __shared__ __align__(16) float Ms[C_][C_];   // 64 KB, whole M (linear DMA dest)
  __shared__ float ps[L_][33];
  __shared__ float dpow[L_+1];
  if (tid <= L_) dpow[tid] = powf(d, (float)tid);

  const float* qp = q + ((size_t)b*T_ + ci*L_)*C_;
  const float* kp = k + ((size_t)b*T_ + ci*L_)*C_;
  const float* vp = v + ((size_t)b*T_ + ci*L_)*C_;
  const float* Mp = Minit + ((size_t)b*NC_ + ci)*C_*C_;

  #pragma unroll
  for (int i=0;i<16;i++){
    int cidx = i*256 + tid;
    gload_lds16(Mp + (size_t)cidx*4, &Ms[0][0] + cidx*4);
  }
  #pragma unroll
  for (int i=0;i<4;i++){
    int idx = tid + i*256;
    int j = idx >> 5, c4 = idx & 31;
    *(float4*)&qs[j][c4*4]  = *(const float4*)(qp + (size_t)j*C_ + c4*4);
    *(float4*)&kvs[j][c4*4] = *(const float4*)(kp + (size_t)j*C_ + c4*4);
  }
  __syncthreads();   // B0: M + qs + kvs(k) visible

  {
    int tr = tid >> 4, tj = tid & 15;
    float s[2][2] = {};
    for (int c4=0;c4<32;c4++){
      float4 q4[2], k4[2];
      #pragma unroll
      for (int i=0;i<2;i++) q4[i] = *(float4*)&qs[tr*2+i][c4*4];
      #pragma unroll
      for (int i=0;i<2;i++) k4[i] = *(float4*)&kvs[tj*2+i][c4*4];
      #pragma unroll
      for (int a=0;a<2;a++)
        #pragma unroll
        for (int bb=0;bb<2;bb++)
          s[a][bb] += q4[a].x*k4[bb].x + q4[a].y*k4[bb].y + q4[a].z*k4[bb].z + q4[a].w*k4[bb].w;
    }
    #pragma unroll
    for (int a=0;a<2;a++)
      #pragma unroll
      for (int bb=0;bb<2;bb++){
        int r = tr*2+a, j = tj*2+bb;
        ps[r][j] = (j < r) ? s[a][bb]*dpow[r-1-j] : 0.f;
      }
  }
  __syncthreads();   // B1: ps visible; kvs(k) dead

  #pragma unroll
  for (int i=0;i<4;i++){
    int idx = tid + i*256;
    int j = idx >> 5, c4 = idx & 31;
    *(float4*)&kvs[j][c4*4] = *(const float4*)(vp + (size_t)j*C_ + c4*4);
  }

  int tx = tid & 31, ty = tid >> 5;
  float acc[4][4] = {};
  for (int c=0;c<C_;c++){
    float4 m4 = *(const float4*)&Ms[c][tx*4];
    #pragma unroll
    for (int r=0;r<4;r++){
      float qv = qs[ty*4+r][c];
      acc[r][0] += qv*m4.x; acc[r][1] += qv*m4.y; acc[r][2] += qv*m4.z; acc[r][3] += qv*m4.w;
    }
  }
  #pragma unroll
  for (int r=0;r<4;r++){
    float sc = dpow[ty*4+r];
    #pragma unroll
    for (int j=0;j<4;j++) acc[r][j] *= sc;
  }
  __syncthreads();   // B2: kvs(v) visible

  for (int j=0;j<L_;j++){
    float4 v4 = *(float4*)&kvs[j][tx*4];
    #pragma unroll
    for (int r=0;r<4;r++){
      float p = ps[ty*4+r][j];
      acc[r][0] += p*v4.x; acc[r][1] += p*v4.y; acc[r][2] += p*v4.z; acc[r][3] += p*v4.w;
    }
  }
  size_t rbase = ((size_t)b*T_ + ci*L_)*C_;
  for (int r=0;r<4;r++){
    union { f16_t h[4]; ushort4 u; } hh;
    #pragma unroll
    for (int j=0;j<4;j++) hh.h[j] = (f16_t)acc[r][j];
    *(ushort4*)(ret + rbase + (size_t)(ty*4+r)*C_ + tx*4) = hh.u;
  }
}

// ---------------------------------------------------------------------------
// K5 (kept, measured best): out = (ret @ Wo^T) * out_scale.
// Barrier-free direct-fragment MFMA. grid (256, 8), 256 thr.
// ---------------------------------------------------------------------------
__global__ __launch_bounds__(256) void out_mfma_kernel(
    const f16_t* __restrict__ A, const f16_t* __restrict__ Bw,
    const float* __restrict__ scl, float* __restrict__ out)
{
  int m0 = blockIdx.x * BM;
  int n0 = blockIdx.y * BN;
  float osc = scl[0];

  int tid  = threadIdx.x;
  int lane = tid & 63;
  int w    = tid >> 6;
  int wm   = (w >> 1) * 32;
  int wn   = (w & 1) * 64;
  int lr   = lane & 15;
  int lg   = lane >> 4;

  f32x4 acc[2][4] = {};

  #pragma unroll
  for (int kh=0; kh<4; kh++){
    f16x8 a[2];
    #pragma unroll
    for (int mt=0; mt<2; mt++)
      a[mt] = *(const f16x8*)(A + (size_t)(m0 + wm + mt*16 + lr)*C_ + kh*32 + lg*8);
    #pragma unroll
    for (int nt=0; nt<4; nt++){
      f16x8 bfr = *(const f16x8*)(Bw + (size_t)(n0 + wn + nt*16 + lr)*C_ + kh*32 + lg*8);
      #pragma unroll
      for (int mt=0; mt<2; mt++)
        acc[mt][nt] = __builtin_amdgcn_mfma_f32_16x16x32_f16(a[mt], bfr, acc[mt][nt], 0,0,0);
    }
  }

  #pragma unroll
  for (int mt=0; mt<2; mt++)
    #pragma unroll
    for (int nt=0; nt<4; nt++)
      #pragma unroll
      for (int r=0; r<4; r++){
        int row = m0 + wm + mt*16 + lg*4 + r;
        int col = n0 + wn + nt*16 + lr;
        out[(size_t)row*V_ + col] = acc[mt][nt][r] * osc;
      }
}

// ---------------------------------------------------------------------------
extern "C" void kernel_launch(void* const* d_in, const int* in_sizes, int n_in,
                              void* d_out, int out_size, void* d_ws, size_t ws_size,
                              hipStream_t stream)
{
  const float* x     = (const float*)d_in[0];
  const float* basis = (const float*)d_in[1];
  const float* qc    = (const float*)d_in[2];
  const float* kc    = (const float*)d_in[3];
  const float* vc    = (const float*)d_in[4];
  const float* oc    = (const float*)d_in[5];
  const float* dptr  = (const float*)d_in[6];
  const float* sptr  = (const float*)d_in[7];
  float* out = (float*)d_out;
  float* ws  = (float*)d_ws;

  const size_t M = (size_t)B_*T_;
  // Workspace layout (offsets in FLOAT units):
  //   Wo   f16 V*C      @ 0        (65536 f)
  //   Wt   f16 3*C*V    @ 65536    (196608 f)
  //   qkv  f32 3*M*C    @ 262144
  //   ret  f16 M*C      @ 6553600
  //   kv   f32 B*NC*C*C @ 7602176
  f16_t* Wo  = (f16_t*)ws;
  f16_t* Wt  = (f16_t*)(ws + 65536);
  float* qkv = ws + 262144;
  f16_t* ret = (f16_t*)(ws + 6553600);
  float* kv  = ws + 7602176;

  float* q = qkv;
  float* k = qkv + M*C_;
  float* v = qkv + 2*M*C_;

  hipLaunchKernelGGL(weights_kernel, dim3(512), dim3(256), 0, stream,
                     basis, qc, kc, vc, oc, Wo, Wt);
  hipLaunchKernelGGL(proj_fused_kernel, dim3(512), dim3(512), 0, stream,
                     x, Wt, qkv);
  hipLaunchKernelGGL(kvsum_kernel, dim3(NC_, B_), dim3(256), 0, stream, k, v, dptr, kv);
  hipLaunchKernelGGL(scan_kernel, dim3(512), dim3(256), 0, stream, kv, dptr);
  hipLaunchKernelGGL(intra_kernel, dim3(NC_, B_), dim3(256), 0, stream,
                     q, k, v, kv, dptr, ret);
  hipLaunchKernelGGL(out_mfma_kernel, dim3(256, 8), dim3(256), 0, stream,
                     ret, Wo, sptr, out);
}

// Round 10
// 257.121 us; speedup vs baseline: 1.0541x; 1.0541x over previous
//
#include <hip/hip_runtime.h>
#include <math.h>

// Problem constants
#define B_   8
#define T_   2048
#define V_   1024
#define C_   128
#define NB2  64     // 2*NB
#define L_   32     // chunk length for the linearized recurrence
#define NC_  64     // T_/L_

typedef _Float16 f16_t;
typedef f16_t f16x8 __attribute__((ext_vector_type(8)));
typedef float f32x4 __attribute__((ext_vector_type(4)));

__device__ __forceinline__ float sigmoidf_(float x){ return 1.0f/(1.0f+expf(-x)); }

// direct global->LDS DMA, 16 B per lane (dest must be linear: base + lane*16)
__device__ __forceinline__ void gload_lds16(const void* g, void* l){
  __builtin_amdgcn_global_load_lds(
      (const __attribute__((address_space(1))) uint32_t*)g,
      (__attribute__((address_space(3))) uint32_t*)l, 16, 0, 0);
}

// ---------------------------------------------------------------------------
// K0: weights. proj 0..2: softmax(basis@coeffs^T, axis=V) -> fp16,
//     TRANSPOSED (Wt[c][v]) for MFMA B-fragment reads.
//     proj 3: Wo (V,C) row-major fp16 (rows are B-fragments for out GEMM).
// ---------------------------------------------------------------------------
__global__ __launch_bounds__(256) void weights_kernel(
    const float* __restrict__ basis,
    const float* __restrict__ qc, const float* __restrict__ kc,
    const float* __restrict__ vc, const float* __restrict__ oc,
    f16_t* __restrict__ Wo, f16_t* __restrict__ Wt)
{
  int blk  = blockIdx.x;
  int proj = blk >> 7;
  int c    = blk & 127;
  const float* coeffs = (proj==0)?qc : (proj==1)?kc : (proj==2)?vc : oc;

  __shared__ float coef[NB2];
  __shared__ float red[256];
  int tid = threadIdx.x;
  if (tid < NB2) coef[tid] = coeffs[c*NB2 + tid];
  __syncthreads();

  float l[4];
  for (int i=0;i<4;i++){
    int v = tid + i*256;
    const float4* bp = (const float4*)(basis + (size_t)v*NB2);
    float s = 0.f;
    #pragma unroll
    for (int f=0; f<NB2/4; f++){
      float4 b4 = bp[f];
      s += b4.x*coef[f*4+0] + b4.y*coef[f*4+1] + b4.z*coef[f*4+2] + b4.w*coef[f*4+3];
    }
    l[i] = s;
  }
  if (proj == 3){
    for (int i=0;i<4;i++){ int v = tid+i*256; Wo[(size_t)v*C_ + c] = (f16_t)l[i]; }
    return;
  }
  float mx = fmaxf(fmaxf(l[0],l[1]), fmaxf(l[2],l[3]));
  red[tid] = mx; __syncthreads();
  for (int s=128; s>0; s>>=1){ if (tid<s) red[tid] = fmaxf(red[tid], red[tid+s]); __syncthreads(); }
  mx = red[0]; __syncthreads();
  float sum = 0.f;
  for (int i=0;i<4;i++) sum += expf(l[i]-mx);
  red[tid] = sum; __syncthreads();
  for (int s=128; s>0; s>>=1){ if (tid<s) red[tid] += red[tid+s]; __syncthreads(); }
  float inv = 1.0f/red[0];
  f16_t* tp = Wt + ((size_t)proj*C_ + c)*V_;
  for (int i=0;i<4;i++){
    int v = tid+i*256;
    tp[v] = (f16_t)(expf(l[i]-mx)*inv);
  }
}

// ---------------------------------------------------------------------------
// K1 v4 (FUSED, BM=64, DOUBLE-BUFFERED 2-phase pipeline):
// q,k,v = x @ [Wq|Wk|Wv] in one pass over x.
// Round-8 (single-buffer): STAGE -> barrier -> MFMA -> barrier; the 48KB
// B-DMA service (~875cy/iter L2 share) fully exposed -> 44us.
// Round-9 (BM=32) FAILED: M-split doubled B-traffic (MfmaUtil 10->8.6).
// Now: As/Bsh x2 (LDS 114.4 KB, 1 block/CU), STAGE(kt) issued BEFORE
// COMPUTE(kt-1), ONE barrier per iter -- T3 minimum 2-phase: DMA latency
// hides under the previous tile's 24 MFMAs.
// 512 thr = 8 waves (2x4), wave tile 32x96, BK=64, 16 K-iters. B staged via
// global_load_lds (linear dest, XOR-swizzled source + same XOR on ds_read).
// ---------------------------------------------------------------------------
#define BM 64     // proj/out M-tile
#define BN 128
#define BK 64
#define PADK 72   // LDS row stride in f16 for A (144 B, breaks pow2 banks)
#define NF_  384  // 3*C
#define NT_PROJ (V_/BK)   // 16

__global__ __launch_bounds__(512, 1) void proj_fused_kernel(
    const float* __restrict__ x,
    const f16_t* __restrict__ Wt,   // [384][1024] f16 (= [3][C][V])
    float* __restrict__ out)        // [3][M][C]
{
  const int M = B_*T_;
  int m0 = blockIdx.x * BM;

  __shared__ __align__(16) f16_t As[2][BM][PADK];  // 18.4 KB
  __shared__ __align__(16) f16_t Bsh[2][NF_*BK];   // 96 KB, swizzled chunks

  int tid  = threadIdx.x;          // 0..511
  int lane = tid & 63;
  int w    = tid >> 6;             // 0..7
  int wm   = (w >> 2) * 32;        // 0,32
  int wn   = (w & 3) * 96;         // 0,96,192,288
  int lr   = lane & 15;
  int lg   = lane >> 4;

  const float* xbase = x + (size_t)m0*V_;

  f32x4 acc[2][6] = {};

#define PROJ_STAGE(buf, kt) do { \
    _Pragma("unroll") \
    for (int i=0;i<6;i++){ \
      int ci = i*512 + tid; \
      int r  = ci >> 3, ch = ci & 7; \
      const f16_t* src = Wt + (size_t)r*V_ + (kt)*BK + ((ch ^ (r&7))<<3); \
      gload_lds16(src, &Bsh[buf][ci*8]); \
    } \
    _Pragma("unroll") \
    for (int i=0;i<2;i++){ \
      int ci = i*512 + tid; \
      int row = ci >> 4, qq = ci & 15; \
      float4 xv = *(const float4*)(xbase + (size_t)row*V_ + (kt)*BK + qq*4); \
      union { f16_t h[4]; ushort4 u; } hh; \
      hh.h[0]=(f16_t)xv.x; hh.h[1]=(f16_t)xv.y; \
      hh.h[2]=(f16_t)xv.z; hh.h[3]=(f16_t)xv.w; \
      *(ushort4*)&As[buf][row][qq*4] = hh.u; \
    } \
  } while(0)

#define PROJ_COMPUTE(buf) do { \
    _Pragma("unroll") \
    for (int kh=0; kh<2; kh++){ \
      f16x8 a[2]; \
      _Pragma("unroll") \
      for (int mt=0; mt<2; mt++) \
        a[mt] = *(f16x8*)&As[buf][wm + mt*16 + lr][kh*32 + lg*8]; \
      _Pragma("unroll") \
      for (int nt=0; nt<6; nt++){ \
        int n  = wn + nt*16 + lr; \
        int c0 = kh*4 + lg; \
        f16x8 b = *(f16x8*)&Bsh[buf][n*BK + ((c0 ^ (n&7))<<3)]; \
        _Pragma("unroll") \
        for (int mt=0; mt<2; mt++) \
          acc[mt][nt] = __builtin_amdgcn_mfma_f32_16x16x32_f16(a[mt], b, acc[mt][nt], 0,0,0); \
      } \
    } \
  } while(0)

  PROJ_STAGE(0, 0);
  __syncthreads();                    // drain tile-0 DMA
  for (int kt=1; kt<NT_PROJ; kt++){
    PROJ_STAGE(kt&1, kt);             // issue next tile's DMA first
    PROJ_COMPUTE((kt-1)&1);           // MFMA on previous tile (hides DMA)
    __syncthreads();                  // one barrier/iter: drains DMA(kt),
  }                                   // frees buf (kt-1)&1 for next STAGE
  PROJ_COMPUTE(1);                    // last tile (15&1 = 1)

#undef PROJ_STAGE
#undef PROJ_COMPUTE

  // epilogue: C/D layout col=lane&15, row=(lane>>4)*4+reg; proj = n>>7
  #pragma unroll
  for (int mt=0; mt<2; mt++)
    #pragma unroll
    for (int nt=0; nt<6; nt++){
      int n   = wn + nt*16 + lr;
      int p   = n >> 7;
      int col = n & 127;
      float* op = out + (size_t)p*M*C_;
      #pragma unroll
      for (int r=0; r<4; r++){
        int row = m0 + wm + mt*16 + lg*4 + r;
        op[(size_t)row*C_ + col] = acc[mt][nt][r];
      }
    }
}

// ---------------------------------------------------------------------------
// K2: per-chunk KV summary: kv[b][ci][c][dd] = sum_j d^{L-1-j} k_j[c] v_j[dd]
// ---------------------------------------------------------------------------
__global__ __launch_bounds__(256) void kvsum_kernel(
    const float* __restrict__ k, const float* __restrict__ v,
    const float* __restrict__ dptr, float* __restrict__ kv)
{
  int ci = blockIdx.x, b = blockIdx.y;
  float d = sigmoidf_(dptr[0]);
  __shared__ float ks[L_][132];
  __shared__ float vs[L_][132];
  int tid = threadIdx.x;
  const float* kp = k + ((size_t)b*T_ + ci*L_)*C_;
  const float* vp = v + ((size_t)b*T_ + ci*L_)*C_;
  #pragma unroll
  for (int i=0;i<4;i++){
    int idx = tid + i*256;
    int j = idx >> 5, c4 = idx & 31;
    float w = powf(d, (float)(L_-1-j));
    float4 k4 = *(const float4*)(kp + (size_t)j*C_ + c4*4);
    k4.x*=w; k4.y*=w; k4.z*=w; k4.w*=w;
    *(float4*)&ks[j][c4*4] = k4;
    *(float4*)&vs[j][c4*4] = *(const float4*)(vp + (size_t)j*C_ + c4*4);
  }
  __syncthreads();
  int tc = tid >> 4, td = tid & 15;
  float acc[8][8] = {};
  for (int j=0;j<L_;j++){
    float kr[8], vr[8];
    *(float4*)&kr[0] = *(float4*)&ks[j][tc*8];
    *(float4*)&kr[4] = *(float4*)&ks[j][tc*8+4];
    *(float4*)&vr[0] = *(float4*)&vs[j][td*8];
    *(float4*)&vr[4] = *(float4*)&vs[j][td*8+4];
    #pragma unroll
    for (int a=0;a<8;a++)
      #pragma unroll
      for (int bb=0;bb<8;bb++) acc[a][bb] += kr[a]*vr[bb];
  }
  float* op = kv + ((size_t)b*NC_ + ci)*C_*C_;
  for (int a=0;a<8;a++)
    for (int b4=0;b4<2;b4++)
      *(float4*)(op + (size_t)(tc*8+a)*C_ + td*8 + b4*4) =
        make_float4(acc[a][b4*4],acc[a][b4*4+1],acc[a][b4*4+2],acc[a][b4*4+3]);
}

// ---------------------------------------------------------------------------
// K3 v2: in-place exclusive scan over chunks, UNROLL-4 load prefetch.
// Bit-exact vs v1 (reads precede the group's writes; addresses disjoint).
// ---------------------------------------------------------------------------
__global__ __launch_bounds__(256) void scan_kernel(
    float* __restrict__ kv, const float* __restrict__ dptr)
{
  int idx = blockIdx.x*256 + threadIdx.x;
  int b = idx >> 14, e = idx & 16383;
  float d  = sigmoidf_(dptr[0]);
  float dL = powf(d, (float)L_);
  float* p = kv + (size_t)b*NC_*C_*C_ + e;
  const size_t S = (size_t)C_*C_;   // 16384
  float m = 0.f;
  #pragma unroll 4
  for (int g=0; g<NC_/4; g++){
    float s0 = p[(size_t)(4*g+0)*S];
    float s1 = p[(size_t)(4*g+1)*S];
    float s2 = p[(size_t)(4*g+2)*S];
    float s3 = p[(size_t)(4*g+3)*S];
    p[(size_t)(4*g+0)*S] = m;  m = dL*m + s0;
    p[(size_t)(4*g+1)*S] = m;  m = dL*m + s1;
    p[(size_t)(4*g+2)*S] = m;  m = dL*m + s2;
    p[(size_t)(4*g+3)*S] = m;  m = dL*m + s3;
  }
}

// ---------------------------------------------------------------------------
// K4 v5 (kept): WHOLE-M intra. 64KB M staged in one global_load_lds burst,
// 3 barriers, q@M as a single unbroken 128-iter LDS loop. 43.7us measured.
// ---------------------------------------------------------------------------
__global__ __launch_bounds__(256) void intra_kernel(
    const float* __restrict__ q, const float* __restrict__ k,
    const float* __restrict__ v, const float* __restrict__ Minit,
    const float* __restrict__ dptr,
    f16_t* __restrict__ ret)
{
  int ci = blockIdx.x, b = blockIdx.y;
  int tid = threadIdx.x;
  float d = sigmoidf_(dptr[0]);
  __shared__ float qs[L_][132];
  __shared__ float kvs[L_][132];               // k for scores, then v
  __shared__ __align__(16) float Ms[C_][C_];   // 64 KB, whole M (linear DMA dest)
  __shared__ float ps[L_][33];
  __shared__ float dpow[L_+1];
  if (tid <= L_) dpow[tid] = powf(d, (float)tid);

  const float* qp = q + ((size_t)b*T_ + ci*L_)*C_;
  const float* kp = k + ((size_t)b*T_ + ci*L_)*C_;
  const float* vp = v + ((size_t)b*T_ + ci*L_)*C_;
  const float* Mp = Minit + ((size_t)b*NC_ + ci)*C_*C_;

  #pragma unroll
  for (int i=0;i<16;i++){
    int cidx = i*256 + tid;
    gload_lds16(Mp + (size_t)cidx*4, &Ms[0][0] + cidx*4);
  }
  #pragma unroll
  for (int i=0;i<4;i++){
    int idx = tid + i*256;
    int j = idx >> 5, c4 = idx & 31;
    *(float4*)&qs[j][c4*4]  = *(const float4*)(qp + (size_t)j*C_ + c4*4);
    *(float4*)&kvs[j][c4*4] = *(const float4*)(kp + (size_t)j*C_ + c4*4);
  }
  __syncthreads();   // B0: M + qs + kvs(k) visible

  {
    int tr = tid >> 4, tj = tid & 15;
    float s[2][2] = {};
    for (int c4=0;c4<32;c4++){
      float4 q4[2], k4[2];
      #pragma unroll
      for (int i=0;i<2;i++) q4[i] = *(float4*)&qs[tr*2+i][c4*4];
      #pragma unroll
      for (int i=0;i<2;i++) k4[i] = *(float4*)&kvs[tj*2+i][c4*4];
      #pragma unroll
      for (int a=0;a<2;a++)
        #pragma unroll
        for (int bb=0;bb<2;bb++)
          s[a][bb] += q4[a].x*k4[bb].x + q4[a].y*k4[bb].y + q4[a].z*k4[bb].z + q4[a].w*k4[bb].w;
    }
    #pragma unroll
    for (int a=0;a<2;a++)
      #pragma unroll
      for (int bb=0;bb<2;bb++){
        int r = tr*2+a, j = tj*2+bb;
        ps[r][j] = (j < r) ? s[a][bb]*dpow[r-1-j] : 0.f;
      }
  }
  __syncthreads();   // B1: ps visible; kvs(k) dead

  #pragma unroll
  for (int i=0;i<4;i++){
    int idx = tid + i*256;
    int j = idx >> 5, c4 = idx & 31;
    *(float4*)&kvs[j][c4*4] = *(const float4*)(vp + (size_t)j*C_ + c4*4);
  }

  int tx = tid & 31, ty = tid >> 5;
  float acc[4][4] = {};
  for (int c=0;c<C_;c++){
    float4 m4 = *(const float4*)&Ms[c][tx*4];
    #pragma unroll
    for (int r=0;r<4;r++){
      float qv = qs[ty*4+r][c];
      acc[r][0] += qv*m4.x; acc[r][1] += qv*m4.y; acc[r][2] += qv*m4.z; acc[r][3] += qv*m4.w;
    }
  }
  #pragma unroll
  for (int r=0;r<4;r++){
    float sc = dpow[ty*4+r];
    #pragma unroll
    for (int j=0;j<4;j++) acc[r][j] *= sc;
  }
  __syncthreads();   // B2: kvs(v) visible

  for (int j=0;j<L_;j++){
    float4 v4 = *(float4*)&kvs[j][tx*4];
    #pragma unroll
    for (int r=0;r<4;r++){
      float p = ps[ty*4+r][j];
      acc[r][0] += p*v4.x; acc[r][1] += p*v4.y; acc[r][2] += p*v4.z; acc[r][3] += p*v4.w;
    }
  }
  size_t rbase = ((size_t)b*T_ + ci*L_)*C_;
  for (int r=0;r<4;r++){
    union { f16_t h[4]; ushort4 u; } hh;
    #pragma unroll
    for (int j=0;j<4;j++) hh.h[j] = (f16_t)acc[r][j];
    *(ushort4*)(ret + rbase + (size_t)(ty*4+r)*C_ + tx*4) = hh.u;
  }
}

// ---------------------------------------------------------------------------
// K5 (kept, measured best): out = (ret @ Wo^T) * out_scale.
// Barrier-free direct-fragment MFMA. grid (256, 8), 256 thr.
// ---------------------------------------------------------------------------
__global__ __launch_bounds__(256) void out_mfma_kernel(
    const f16_t* __restrict__ A, const f16_t* __restrict__ Bw,
    const float* __restrict__ scl, float* __restrict__ out)
{
  int m0 = blockIdx.x * BM;
  int n0 = blockIdx.y * BN;
  float osc = scl[0];

  int tid  = threadIdx.x;
  int lane = tid & 63;
  int w    = tid >> 6;
  int wm   = (w >> 1) * 32;
  int wn   = (w & 1) * 64;
  int lr   = lane & 15;
  int lg   = lane >> 4;

  f32x4 acc[2][4] = {};

  #pragma unroll
  for (int kh=0; kh<4; kh++){
    f16x8 a[2];
    #pragma unroll
    for (int mt=0; mt<2; mt++)
      a[mt] = *(const f16x8*)(A + (size_t)(m0 + wm + mt*16 + lr)*C_ + kh*32 + lg*8);
    #pragma unroll
    for (int nt=0; nt<4; nt++){
      f16x8 bfr = *(const f16x8*)(Bw + (size_t)(n0 + wn + nt*16 + lr)*C_ + kh*32 + lg*8);
      #pragma unroll
      for (int mt=0; mt<2; mt++)
        acc[mt][nt] = __builtin_amdgcn_mfma_f32_16x16x32_f16(a[mt], bfr, acc[mt][nt], 0,0,0);
    }
  }

  #pragma unroll
  for (int mt=0; mt<2; mt++)
    #pragma unroll
    for (int nt=0; nt<4; nt++)
      #pragma unroll
      for (int r=0; r<4; r++){
        int row = m0 + wm + mt*16 + lg*4 + r;
        int col = n0 + wn + nt*16 + lr;
        out[(size_t)row*V_ + col] = acc[mt][nt][r] * osc;
      }
}

// ---------------------------------------------------------------------------
extern "C" void kernel_launch(void* const* d_in, const int* in_sizes, int n_in,
                              void* d_out, int out_size, void* d_ws, size_t ws_size,
                              hipStream_t stream)
{
  const float* x     = (const float*)d_in[0];
  const float* basis = (const float*)d_in[1];
  const float* qc    = (const float*)d_in[2];
  const float* kc    = (const float*)d_in[3];
  const float* vc    = (const float*)d_in[4];
  const float* oc    = (const float*)d_in[5];
  const float* dptr  = (const float*)d_in[6];
  const float* sptr  = (const float*)d_in[7];
  float* out = (float*)d_out;
  float* ws  = (float*)d_ws;

  const size_t M = (size_t)B_*T_;
  // Workspace layout (offsets in FLOAT units):
  //   Wo   f16 V*C      @ 0        (65536 f)
  //   Wt   f16 3*C*V    @ 65536    (196608 f)
  //   qkv  f32 3*M*C    @ 262144
  //   ret  f16 M*C      @ 6553600
  //   kv   f32 B*NC*C*C @ 7602176
  f16_t* Wo  = (f16_t*)ws;
  f16_t* Wt  = (f16_t*)(ws + 65536);
  float* qkv = ws + 262144;
  f16_t* ret = (f16_t*)(ws + 6553600);
  float* kv  = ws + 7602176;

  float* q = qkv;
  float* k = qkv + M*C_;
  float* v = qkv + 2*M*C_;

  hipLaunchKernelGGL(weights_kernel, dim3(512), dim3(256), 0, stream,
                     basis, qc, kc, vc, oc, Wo, Wt);
  hipLaunchKernelGGL(proj_fused_kernel, dim3(256), dim3(512), 0, stream,
                     x, Wt, qkv);
  hipLaunchKernelGGL(kvsum_kernel, dim3(NC_, B_), dim3(256), 0, stream, k, v, dptr, kv);
  hipLaunchKernelGGL(scan_kernel, dim3(512), dim3(256), 0, stream, kv, dptr);
  hipLaunchKernelGGL(intra_kernel, dim3(NC_, B_), dim3(256), 0, stream,
                     q, k, v, kv, dptr, ret);
  hipLaunchKernelGGL(out_mfma_kernel, dim3(256, 8), dim3(256), 0, stream,
                     ret, Wo, sptr, out);
}

// Round 11
// 255.141 us; speedup vs baseline: 1.0623x; 1.0078x over previous
//
#include <hip/hip_runtime.h>
#include <math.h>

// Problem constants
#define B_   8
#define T_   2048
#define V_   1024
#define C_   128
#define NB2  64     // 2*NB
#define L_   32     // chunk length for the linearized recurrence
#define NC_  64     // T_/L_

typedef _Float16 f16_t;
typedef f16_t f16x8 __attribute__((ext_vector_type(8)));
typedef float f32x4 __attribute__((ext_vector_type(4)));

__device__ __forceinline__ float sigmoidf_(float x){ return 1.0f/(1.0f+expf(-x)); }

// direct global->LDS DMA, 16 B per lane (dest must be linear: base + lane*16)
__device__ __forceinline__ void gload_lds16(const void* g, void* l){
  __builtin_amdgcn_global_load_lds(
      (const __attribute__((address_space(1))) uint32_t*)g,
      (__attribute__((address_space(3))) uint32_t*)l, 16, 0, 0);
}

// ---------------------------------------------------------------------------
// K0: weights. proj 0..2: softmax(basis@coeffs^T, axis=V) -> fp16,
//     TRANSPOSED (Wt[c][v]) for MFMA B-fragment reads.
//     proj 3: Wo (V,C) row-major fp16 (rows are B-fragments for out GEMM).
// ---------------------------------------------------------------------------
__global__ __launch_bounds__(256) void weights_kernel(
    const float* __restrict__ basis,
    const float* __restrict__ qc, const float* __restrict__ kc,
    const float* __restrict__ vc, const float* __restrict__ oc,
    f16_t* __restrict__ Wo, f16_t* __restrict__ Wt)
{
  int blk  = blockIdx.x;
  int proj = blk >> 7;
  int c    = blk & 127;
  const float* coeffs = (proj==0)?qc : (proj==1)?kc : (proj==2)?vc : oc;

  __shared__ float coef[NB2];
  __shared__ float red[256];
  int tid = threadIdx.x;
  if (tid < NB2) coef[tid] = coeffs[c*NB2 + tid];
  __syncthreads();

  float l[4];
  for (int i=0;i<4;i++){
    int v = tid + i*256;
    const float4* bp = (const float4*)(basis + (size_t)v*NB2);
    float s = 0.f;
    #pragma unroll
    for (int f=0; f<NB2/4; f++){
      float4 b4 = bp[f];
      s += b4.x*coef[f*4+0] + b4.y*coef[f*4+1] + b4.z*coef[f*4+2] + b4.w*coef[f*4+3];
    }
    l[i] = s;
  }
  if (proj == 3){
    for (int i=0;i<4;i++){ int v = tid+i*256; Wo[(size_t)v*C_ + c] = (f16_t)l[i]; }
    return;
  }
  float mx = fmaxf(fmaxf(l[0],l[1]), fmaxf(l[2],l[3]));
  red[tid] = mx; __syncthreads();
  for (int s=128; s>0; s>>=1){ if (tid<s) red[tid] = fmaxf(red[tid], red[tid+s]); __syncthreads(); }
  mx = red[0]; __syncthreads();
  float sum = 0.f;
  for (int i=0;i<4;i++) sum += expf(l[i]-mx);
  red[tid] = sum; __syncthreads();
  for (int s=128; s>0; s>>=1){ if (tid<s) red[tid] += red[tid+s]; __syncthreads(); }
  float inv = 1.0f/red[0];
  f16_t* tp = Wt + ((size_t)proj*C_ + c)*V_;
  for (int i=0;i<4;i++){
    int v = tid+i*256;
    tp[v] = (f16_t)(expf(l[i]-mx)*inv);
  }
}

// ---------------------------------------------------------------------------
// K1 v5 (FUSED proj + kvsum): q,k,v = x @ [Wq|Wk|Wv], AND the per-chunk
// decay-weighted kv outer-product summary, in one kernel.
// A proj block (64 rows, one batch) holds k,v for EXACTLY 2 chunks in its
// accumulators -- kvsum's HBM round-trip (write k,v; re-read 16 MB; separate
// dispatch) is pure overhead. Epilogue: stash k (pre-scaled d^(31-j), same
// op order as kvsum -> bit-exact) and v into LDS aliased onto the dead
// As/Bsh pool, then run kvsum's exact 8x8 outer-product and write kv.
// K-loop = round-8 single-buffer (measured == dbuf; dbuf gave nothing).
// LDS pool 66 KB (K-loop 58.4 / epilogue 66), 512 thr.
// ---------------------------------------------------------------------------
#define BM 64
#define BN 128
#define BK 64
#define PADK 72   // LDS row stride in f16 for A (144 B, breaks pow2 banks)
#define NF_  384  // 3*C
#define NT_PROJ (V_/BK)   // 16
#define KVPAD 132 // f32 row stride for ks/vs (matches kvsum's anti-conflict pad)

__global__ __launch_bounds__(512, 1) void proj_fused_kernel(
    const float* __restrict__ x,
    const f16_t* __restrict__ Wt,   // [384][1024] f16 (= [3][C][V])
    const float* __restrict__ dptr,
    float* __restrict__ out,        // qkv [3][M][C]
    float* __restrict__ kv)         // [B][NC][C][C]
{
  const int M = B_*T_;
  int m0 = blockIdx.x * BM;

  // Flat LDS pool, phase-aliased:
  //   K-loop:   As  f16[64][PADK] @ float 0     (2304 f)
  //             Bsh f16[NF_*BK]   @ float 2304  (12288 f)  -> 14592 f used
  //   epilogue: ks  f32[2][32][KVPAD] @ 0       (8448 f)
  //             vs  f32[2][32][KVPAD] @ 8448    (8448 f)   -> 16896 f used
  __shared__ __align__(16) float pool[16896];   // 66 KB
  __shared__ float dpow[L_];
  f16_t* As  = (f16_t*)pool;              // As[row][q] = As[row*PADK + q]
  f16_t* Bsh = (f16_t*)pool + 64*PADK;    // [NF_*BK], swizzled chunks
  float* ks  = pool;                      // [2][32][KVPAD] (after K-loop)
  float* vs  = pool + 8448;

  int tid  = threadIdx.x;          // 0..511
  int lane = tid & 63;
  int w    = tid >> 6;             // 0..7
  int wm   = (w >> 2) * 32;        // 0,32
  int wn   = (w & 3) * 96;         // 0,96,192,288
  int lr   = lane & 15;
  int lg   = lane >> 4;

  float d = sigmoidf_(dptr[0]);
  if (tid < L_) dpow[tid] = powf(d, (float)tid);  // read only in epilogue

  const float* xbase = x + (size_t)m0*V_;

  f32x4 acc[2][6] = {};

  for (int kt = 0; kt < NT_PROJ; kt++){
    // B: 384x64 f16 = 3072 16B chunks, 6/thread, DMA to LDS (linear dest,
    // source XOR-swizzled; same XOR on the read below).
    #pragma unroll
    for (int i=0;i<6;i++){
      int ci = i*512 + tid;
      int r  = ci >> 3, ch = ci & 7;
      const f16_t* src = Wt + (size_t)r*V_ + kt*BK + ((ch ^ (r&7))<<3);
      gload_lds16(src, &Bsh[ci*8]);
    }
    // A: 64x64 fp32 -> f16, 1024 float4 chunks, 2/thread
    #pragma unroll
    for (int i=0;i<2;i++){
      int ci = i*512 + tid;
      int row = ci >> 4, qq = ci & 15;
      float4 xv = *(const float4*)(xbase + (size_t)row*V_ + kt*BK + qq*4);
      union { f16_t h[4]; ushort4 u; } hh;
      hh.h[0]=(f16_t)xv.x; hh.h[1]=(f16_t)xv.y; hh.h[2]=(f16_t)xv.z; hh.h[3]=(f16_t)xv.w;
      *(ushort4*)&As[row*PADK + qq*4] = hh.u;
    }
    __syncthreads();

    #pragma unroll
    for (int kh=0; kh<2; kh++){
      f16x8 a[2];
      #pragma unroll
      for (int mt=0; mt<2; mt++)
        a[mt] = *(f16x8*)&As[(wm + mt*16 + lr)*PADK + kh*32 + lg*8];
      #pragma unroll
      for (int nt=0; nt<6; nt++){
        int n  = wn + nt*16 + lr;
        int c0 = kh*4 + lg;
        f16x8 b = *(f16x8*)&Bsh[n*BK + ((c0 ^ (n&7))<<3)];
        #pragma unroll
        for (int mt=0; mt<2; mt++)
          acc[mt][nt] = __builtin_amdgcn_mfma_f32_16x16x32_f16(a[mt], b, acc[mt][nt], 0,0,0);
      }
    }
    __syncthreads();   // also fences: next iter overwrites As/Bsh
  }
  // After the final barrier above, As/Bsh are dead -> pool reusable as ks/vs.

  // ---- epilogue A: global q,k,v writes + stash k (scaled), v into LDS.
  // C/D layout col=lane&15, row=(lane>>4)*4+reg; proj p = n>>7.
  #pragma unroll
  for (int mt=0; mt<2; mt++)
    #pragma unroll
    for (int nt=0; nt<6; nt++){
      int n   = wn + nt*16 + lr;
      int p   = n >> 7;
      int col = n & 127;
      float* op = out + (size_t)p*M*C_;
      #pragma unroll
      for (int r=0; r<4; r++){
        int row64 = wm + mt*16 + lg*4 + r;
        float val = acc[mt][nt][r];
        op[(size_t)(m0 + row64)*C_ + col] = val;
        int chnk = row64 >> 5, jrow = row64 & 31;
        if (p == 1)
          ks[chnk*(L_*KVPAD) + jrow*KVPAD + col] = val * dpow[L_-1-jrow];
        else if (p == 2)
          vs[chnk*(L_*KVPAD) + jrow*KVPAD + col] = val;
      }
    }
  __syncthreads();   // ks/vs complete

  // ---- epilogue B: kvsum's exact outer-product, 2 chunks x 256 threads
  {
    int chnk = tid >> 8;          // 0,1
    int t2   = tid & 255;
    int tc   = t2 >> 4, td = t2 & 15;
    const float* ksp = ks + chnk*(L_*KVPAD);
    const float* vsp = vs + chnk*(L_*KVPAD);
    float a8[8][8] = {};
    for (int j=0;j<L_;j++){
      float kr[8], vr[8];
      *(float4*)&kr[0] = *(const float4*)&ksp[j*KVPAD + tc*8];
      *(float4*)&kr[4] = *(const float4*)&ksp[j*KVPAD + tc*8+4];
      *(float4*)&vr[0] = *(const float4*)&vsp[j*KVPAD + td*8];
      *(float4*)&vr[4] = *(const float4*)&vsp[j*KVPAD + td*8+4];
      #pragma unroll
      for (int a=0;a<8;a++)
        #pragma unroll
        for (int bb=0;bb<8;bb++) a8[a][bb] += kr[a]*vr[bb];
    }
    int bb_  = m0 >> 11;              // batch
    int ci0  = (m0 & (T_-1)) >> 5;    // first chunk index
    float* op2 = kv + ((size_t)bb_*NC_ + ci0 + chnk)*C_*C_;
    for (int a=0;a<8;a++)
      for (int b4=0;b4<2;b4++)
        *(float4*)(op2 + (size_t)(tc*8+a)*C_ + td*8 + b4*4) =
          make_float4(a8[a][b4*4],a8[a][b4*4+1],a8[a][b4*4+2],a8[a][b4*4+3]);
  }
}

// ---------------------------------------------------------------------------
// K3 v2: in-place exclusive scan over chunks, UNROLL-4 load prefetch.
// Bit-exact vs v1 (reads precede the group's writes; addresses disjoint).
// ---------------------------------------------------------------------------
__global__ __launch_bounds__(256) void scan_kernel(
    float* __restrict__ kv, const float* __restrict__ dptr)
{
  int idx = blockIdx.x*256 + threadIdx.x;
  int b = idx >> 14, e = idx & 16383;
  float d  = sigmoidf_(dptr[0]);
  float dL = powf(d, (float)L_);
  float* p = kv + (size_t)b*NC_*C_*C_ + e;
  const size_t S = (size_t)C_*C_;   // 16384
  float m = 0.f;
  #pragma unroll 4
  for (int g=0; g<NC_/4; g++){
    float s0 = p[(size_t)(4*g+0)*S];
    float s1 = p[(size_t)(4*g+1)*S];
    float s2 = p[(size_t)(4*g+2)*S];
    float s3 = p[(size_t)(4*g+3)*S];
    p[(size_t)(4*g+0)*S] = m;  m = dL*m + s0;
    p[(size_t)(4*g+1)*S] = m;  m = dL*m + s1;
    p[(size_t)(4*g+2)*S] = m;  m = dL*m + s2;
    p[(size_t)(4*g+3)*S] = m;  m = dL*m + s3;
  }
}

// ---------------------------------------------------------------------------
// K4 v5 (kept): WHOLE-M intra. 64KB M staged in one global_load_lds burst,
// 3 barriers, q@M as a single unbroken 128-iter LDS loop. 43.7us measured.
// ---------------------------------------------------------------------------
__global__ __launch_bounds__(256) void intra_kernel(
    const float* __restrict__ q, const float* __restrict__ k,
    const float* __restrict__ v, const float* __restrict__ Minit,
    const float* __restrict__ dptr,
    f16_t* __restrict__ ret)
{
  int ci = blockIdx.x, b = blockIdx.y;
  int tid = threadIdx.x;
  float d = sigmoidf_(dptr[0]);
  __shared__ float qs[L_][132];
  __shared__ float kvs[L_][132];               // k for scores, then v
  __shared__ __align__(16) float Ms[C_][C_];   // 64 KB, whole M (linear DMA dest)
  __shared__ float ps[L_][33];
  __shared__ float dpow[L_+1];
  if (tid <= L_) dpow[tid] = powf(d, (float)tid);

  const float* qp = q + ((size_t)b*T_ + ci*L_)*C_;
  const float* kp = k + ((size_t)b*T_ + ci*L_)*C_;
  const float* vp = v + ((size_t)b*T_ + ci*L_)*C_;
  const float* Mp = Minit + ((size_t)b*NC_ + ci)*C_*C_;

  #pragma unroll
  for (int i=0;i<16;i++){
    int cidx = i*256 + tid;
    gload_lds16(Mp + (size_t)cidx*4, &Ms[0][0] + cidx*4);
  }
  #pragma unroll
  for (int i=0;i<4;i++){
    int idx = tid + i*256;
    int j = idx >> 5, c4 = idx & 31;
    *(float4*)&qs[j][c4*4]  = *(const float4*)(qp + (size_t)j*C_ + c4*4);
    *(float4*)&kvs[j][c4*4] = *(const float4*)(kp + (size_t)j*C_ + c4*4);
  }
  __syncthreads();   // B0: M + qs + kvs(k) visible

  {
    int tr = tid >> 4, tj = tid & 15;
    float s[2][2] = {};
    for (int c4=0;c4<32;c4++){
      float4 q4[2], k4[2];
      #pragma unroll
      for (int i=0;i<2;i++) q4[i] = *(float4*)&qs[tr*2+i][c4*4];
      #pragma unroll
      for (int i=0;i<2;i++) k4[i] = *(float4*)&kvs[tj*2+i][c4*4];
      #pragma unroll
      for (int a=0;a<2;a++)
        #pragma unroll
        for (int bb=0;bb<2;bb++)
          s[a][bb] += q4[a].x*k4[bb].x + q4[a].y*k4[bb].y + q4[a].z*k4[bb].z + q4[a].w*k4[bb].w;
    }
    #pragma unroll
    for (int a=0;a<2;a++)
      #pragma unroll
      for (int bb=0;bb<2;bb++){
        int r = tr*2+a, j = tj*2+bb;
        ps[r][j] = (j < r) ? s[a][bb]*dpow[r-1-j] : 0.f;
      }
  }
  __syncthreads();   // B1: ps visible; kvs(k) dead

  #pragma unroll
  for (int i=0;i<4;i++){
    int idx = tid + i*256;
    int j = idx >> 5, c4 = idx & 31;
    *(float4*)&kvs[j][c4*4] = *(const float4*)(vp + (size_t)j*C_ + c4*4);
  }

  int tx = tid & 31, ty = tid >> 5;
  float acc[4][4] = {};
  for (int c=0;c<C_;c++){
    float4 m4 = *(const float4*)&Ms[c][tx*4];
    #pragma unroll
    for (int r=0;r<4;r++){
      float qv = qs[ty*4+r][c];
      acc[r][0] += qv*m4.x; acc[r][1] += qv*m4.y; acc[r][2] += qv*m4.z; acc[r][3] += qv*m4.w;
    }
  }
  #pragma unroll
  for (int r=0;r<4;r++){
    float sc = dpow[ty*4+r];
    #pragma unroll
    for (int j=0;j<4;j++) acc[r][j] *= sc;
  }
  __syncthreads();   // B2: kvs(v) visible

  for (int j=0;j<L_;j++){
    float4 v4 = *(float4*)&kvs[j][tx*4];
    #pragma unroll
    for (int r=0;r<4;r++){
      float p = ps[ty*4+r][j];
      acc[r][0] += p*v4.x; acc[r][1] += p*v4.y; acc[r][2] += p*v4.z; acc[r][3] += p*v4.w;
    }
  }
  size_t rbase = ((size_t)b*T_ + ci*L_)*C_;
  for (int r=0;r<4;r++){
    union { f16_t h[4]; ushort4 u; } hh;
    #pragma unroll
    for (int j=0;j<4;j++) hh.h[j] = (f16_t)acc[r][j];
    *(ushort4*)(ret + rbase + (size_t)(ty*4+r)*C_ + tx*4) = hh.u;
  }
}

// ---------------------------------------------------------------------------
// K5 (kept, measured best): out = (ret @ Wo^T) * out_scale.
// Barrier-free direct-fragment MFMA. grid (256, 8), 256 thr.
// ---------------------------------------------------------------------------
__global__ __launch_bounds__(256) void out_mfma_kernel(
    const f16_t* __restrict__ A, const f16_t* __restrict__ Bw,
    const float* __restrict__ scl, float* __restrict__ out)
{
  int m0 = blockIdx.x * BM;
  int n0 = blockIdx.y * BN;
  float osc = scl[0];

  int tid  = threadIdx.x;
  int lane = tid & 63;
  int w    = tid >> 6;
  int wm   = (w >> 1) * 32;
  int wn   = (w & 1) * 64;
  int lr   = lane & 15;
  int lg   = lane >> 4;

  f32x4 acc[2][4] = {};

  #pragma unroll
  for (int kh=0; kh<4; kh++){
    f16x8 a[2];
    #pragma unroll
    for (int mt=0; mt<2; mt++)
      a[mt] = *(const f16x8*)(A + (size_t)(m0 + wm + mt*16 + lr)*C_ + kh*32 + lg*8);
    #pragma unroll
    for (int nt=0; nt<4; nt++){
      f16x8 bfr = *(const f16x8*)(Bw + (size_t)(n0 + wn + nt*16 + lr)*C_ + kh*32 + lg*8);
      #pragma unroll
      for (int mt=0; mt<2; mt++)
        acc[mt][nt] = __builtin_amdgcn_mfma_f32_16x16x32_f16(a[mt], bfr, acc[mt][nt], 0,0,0);
    }
  }

  #pragma unroll
  for (int mt=0; mt<2; mt++)
    #pragma unroll
    for (int nt=0; nt<4; nt++)
      #pragma unroll
      for (int r=0; r<4; r++){
        int row = m0 + wm + mt*16 + lg*4 + r;
        int col = n0 + wn + nt*16 + lr;
        out[(size_t)row*V_ + col] = acc[mt][nt][r] * osc;
      }
}

// ---------------------------------------------------------------------------
extern "C" void kernel_launch(void* const* d_in, const int* in_sizes, int n_in,
                              void* d_out, int out_size, void* d_ws, size_t ws_size,
                              hipStream_t stream)
{
  const float* x     = (const float*)d_in[0];
  const float* basis = (const float*)d_in[1];
  const float* qc    = (const float*)d_in[2];
  const float* kc    = (const float*)d_in[3];
  const float* vc    = (const float*)d_in[4];
  const float* oc    = (const float*)d_in[5];
  const float* dptr  = (const float*)d_in[6];
  const float* sptr  = (const float*)d_in[7];
  float* out = (float*)d_out;
  float* ws  = (float*)d_ws;

  const size_t M = (size_t)B_*T_;
  // Workspace layout (offsets in FLOAT units):
  //   Wo   f16 V*C      @ 0        (65536 f)
  //   Wt   f16 3*C*V    @ 65536    (196608 f)
  //   qkv  f32 3*M*C    @ 262144
  //   ret  f16 M*C      @ 6553600
  //   kv   f32 B*NC*C*C @ 7602176
  f16_t* Wo  = (f16_t*)ws;
  f16_t* Wt  = (f16_t*)(ws + 65536);
  float* qkv = ws + 262144;
  f16_t* ret = (f16_t*)(ws + 6553600);
  float* kv  = ws + 7602176;

  float* q = qkv;
  float* k = qkv + M*C_;
  float* v = qkv + 2*M*C_;

  hipLaunchKernelGGL(weights_kernel, dim3(512), dim3(256), 0, stream,
                     basis, qc, kc, vc, oc, Wo, Wt);
  hipLaunchKernelGGL(proj_fused_kernel, dim3(256), dim3(512), 0, stream,
                     x, Wt, dptr, qkv, kv);
  hipLaunchKernelGGL(scan_kernel, dim3(512), dim3(256), 0, stream, kv, dptr);
  hipLaunchKernelGGL(intra_kernel, dim3(NC_, B_), dim3(256), 0, stream,
                     q, k, v, kv, dptr, ret);
  hipLaunchKernelGGL(out_mfma_kernel, dim3(256, 8), dim3(256), 0, stream,
                     ret, Wo, sptr, out);
}